// Round 1
// 968.981 us; speedup vs baseline: 1.1932x; 1.1932x over previous
//
#include <hip/hip_runtime.h>
#include <hip/hip_bf16.h>
#include <math.h>

#define NNODES 50000
#define NEDGES 800000
#define HID    128
#define NB_SCAN 196   // ceil(50000/256)

typedef short bf16x8 __attribute__((ext_vector_type(8)));
typedef float f32x4  __attribute__((ext_vector_type(4)));

__device__ __forceinline__ unsigned short bf16_rn(float x) {
    union { float f; unsigned int u; } v; v.f = x;
    unsigned int r = v.u + 0x7fffu + ((v.u >> 16) & 1u);
    return (unsigned short)(r >> 16);
}
__device__ __forceinline__ float bf16_to_f(unsigned short u) {
    union { unsigned int u; float f; } v; v.u = ((unsigned int)u) << 16;
    return v.f;
}

// ---------------------------------------------------------------------------
// K0: transpose Wc (=W1[256:384]) into Wt[c][k] bf16 (32 KB, L2/L1 resident)
// ---------------------------------------------------------------------------
__global__ void k_prep(const float* __restrict__ W1, unsigned short* __restrict__ Wt)
{
    const float* Wc = W1 + 256 * 128;
    int t = threadIdx.x;
    for (int i = 0; i < 64; ++i) {
        int idx = t * 64 + i;
        int c = idx >> 7, k = idx & 127;
        Wt[c * 128 + k] = bf16_rn(Wc[k * 128 + c]);
    }
}

// ---------------------------------------------------------------------------
// K1: node GEMM -> Hab bf16.  c<128: (h@Wa)[n][c]+b1[c];  c>=128: (h@Wb)[n][c-128]
// ---------------------------------------------------------------------------
__global__ __launch_bounds__(256) void k_gemm_node(
    const float* __restrict__ h, const float* __restrict__ W1,
    const float* __restrict__ b1, unsigned short* __restrict__ Hab)
{
    __shared__ float at[32][132];
    __shared__ float bt[32][128];

    const int tid = threadIdx.x;
    const int tx  = tid & 15;
    const int ty  = tid >> 4;
    const int nb  = blockIdx.x * 128;
    const int by  = blockIdx.y;
    const float* W = W1 + by * 128 * 128;

    float acc[8][8];
#pragma unroll
    for (int j = 0; j < 8; ++j)
#pragma unroll
        for (int c = 0; c < 8; ++c) acc[j][c] = 0.0f;

    for (int ks = 0; ks < 128; ks += 32) {
#pragma unroll
        for (int p = 0; p < 16; ++p) {
            int i  = (tid >> 5) + p * 8;
            int kk = tid & 31;
            int n  = nb + i;
            at[kk][i] = (n < NNODES) ? h[n * 128 + ks + kk] : 0.0f;
        }
#pragma unroll
        for (int p = 0; p < 16; ++p) {
            int kk = (tid >> 7) + p * 2;
            int c  = tid & 127;
            bt[kk][c] = W[(ks + kk) * 128 + c];
        }
        __syncthreads();
#pragma unroll
        for (int k = 0; k < 32; ++k) {
            float av[8], bv[8];
            *(float4*)&av[0] = *(const float4*)&at[k][ty * 8];
            *(float4*)&av[4] = *(const float4*)&at[k][ty * 8 + 4];
            *(float4*)&bv[0] = *(const float4*)&bt[k][tx * 8];
            *(float4*)&bv[4] = *(const float4*)&bt[k][tx * 8 + 4];
#pragma unroll
            for (int j = 0; j < 8; ++j)
#pragma unroll
                for (int c = 0; c < 8; ++c)
                    acc[j][c] = fmaf(av[j], bv[c], acc[j][c]);
        }
        __syncthreads();
    }

    float b1v[8];
    if (by == 0) {
        *(float4*)&b1v[0] = *(const float4*)&b1[tx * 8];
        *(float4*)&b1v[4] = *(const float4*)&b1[tx * 8 + 4];
    } else {
#pragma unroll
        for (int c = 0; c < 8; ++c) b1v[c] = 0.0f;
    }
#pragma unroll
    for (int j = 0; j < 8; ++j) {
        int n = nb + ty * 8 + j;
        if (n < NNODES) {
            unsigned short o[8];
#pragma unroll
            for (int c = 0; c < 8; ++c) o[c] = bf16_rn(acc[j][c] + b1v[c]);
            unsigned short* dst = Hab + (size_t)n * 256 + by * 128 + tx * 8;
            *(int4*)dst = *(int4*)&o[0];
        }
    }
}

// ---------------------------------------------------------------------------
// K2: edge GEMM via bf16 MFMA, zero LDS.
// Block = 256 (4 waves), 128 edges/block. Each wave owns 32 edges x ALL 128
// channels (acc[2][8] tiles of 16x16x32) so the per-edge W2-dot is wave-local.
// CHANNEL PERMUTATION: B-tile nt, MFMA col lm now maps to actual channel
// lm*8+nt (was nt*16+lm). The mapping is a bijection over [0,128); since the
// epilogue sums over all channels, only three places must agree: the bfrag
// index into Wt, the Hab gather address, and the W2 address. With this
// permutation each lane's 8 Ha/Hb channels are CONTIGUOUS -> one bf16x8
// (16 B) load per edge-half instead of 8 scalar 2 B loads, and each quad's
// 16 lanes read the full 256 B row coalesced.
// C/D layout: col=lane&15, row=quad*4+reg (edge).
// ---------------------------------------------------------------------------
__global__ __launch_bounds__(256) void k_edge_mfma(
    const float* __restrict__ ea, const int* __restrict__ eidx,
    const unsigned short* __restrict__ Wt, const float* __restrict__ W2,
    const float* __restrict__ b2, const unsigned short* __restrict__ Hab,
    float* __restrict__ a_out)
{
    const int tid  = threadIdx.x;
    const int w    = tid >> 6;
    const int l    = tid & 63;
    const int quad = l >> 4;
    const int lm   = l & 15;
    const int wm   = w * 32;                 // 32 edges per wave
    const int ebase = blockIdx.x * 128;

    f32x4 acc[2][8] = {};

    // hoist edge-index loads: in flight during the 4 MFMA stages
    int rows0[4], cols0[4], rows1[4], cols1[4];
    {
        const int e40 = ebase + wm + 0 * 16 + quad * 4;
        const int e41 = ebase + wm + 1 * 16 + quad * 4;
#pragma unroll
        for (int r = 0; r < 4; ++r) {
            rows0[r] = eidx[e40 + r];
            cols0[r] = eidx[NEDGES + e40 + r];
            rows1[r] = eidx[e41 + r];
            cols1[r] = eidx[NEDGES + e41 + r];
        }
    }

#pragma unroll
    for (int stage = 0; stage < 4; ++stage) {
        const int ks = stage * 32;
        bf16x8 bfrag[8];
#pragma unroll
        for (int nt = 0; nt < 8; ++nt) {
            // channel = lm*8 + nt  (permuted mapping)
            const unsigned short* bp = Wt + (lm * 8 + nt) * 128 + ks + quad * 8;
            bfrag[nt] = *(const bf16x8*)bp;
        }
        bf16x8 afrag[2];
#pragma unroll
        for (int mt = 0; mt < 2; ++mt) {
            const float* ap = ea + (size_t)(ebase + wm + mt * 16 + lm) * 128 + ks + quad * 8;
            float4 x0 = *(const float4*)ap;
            float4 x1 = *(const float4*)(ap + 4);
            bf16x8 f;
            f[0] = (short)bf16_rn(x0.x); f[1] = (short)bf16_rn(x0.y);
            f[2] = (short)bf16_rn(x0.z); f[3] = (short)bf16_rn(x0.w);
            f[4] = (short)bf16_rn(x1.x); f[5] = (short)bf16_rn(x1.y);
            f[6] = (short)bf16_rn(x1.z); f[7] = (short)bf16_rn(x1.w);
            afrag[mt] = f;
        }
#pragma unroll
        for (int mt = 0; mt < 2; ++mt)
#pragma unroll
            for (int nt = 0; nt < 8; ++nt)
                acc[mt][nt] = __builtin_amdgcn_mfma_f32_16x16x32_bf16(
                    afrag[mt], bfrag[nt], acc[mt][nt], 0, 0, 0);
    }

    // epilogue: per edge, pre[c] = acc + Ha[row][c] + Hb[col][c]; elu; dot W2
    // channel for (nt,lm) is lm*8+nt -> contiguous per-lane Hab/W2 access.
    float w2v[8];
    *(float4*)&w2v[0] = *(const float4*)&W2[lm * 8];
    *(float4*)&w2v[4] = *(const float4*)&W2[lm * 8 + 4];
    const float b2s = b2[0];

#pragma unroll
    for (int mt = 0; mt < 2; ++mt) {
        const int e4 = ebase + wm + mt * 16 + quad * 4;   // 4 edges of this quad

        // batch the 8 vector gathers so all are outstanding together
        bf16x8 hav[4], hbv[4];
#pragma unroll
        for (int r = 0; r < 4; ++r) {
            int row  = (mt == 0) ? rows0[r] : rows1[r];
            int colj = (mt == 0) ? cols0[r] : cols1[r];
            hav[r] = *(const bf16x8*)(Hab + (size_t)row  * 256 + lm * 8);
            hbv[r] = *(const bf16x8*)(Hab + (size_t)colj * 256 + 128 + lm * 8);
        }

        float s0 = 0.f, s1 = 0.f, s2 = 0.f, s3 = 0.f;
#pragma unroll
        for (int r = 0; r < 4; ++r) {
            float sr = 0.f;
#pragma unroll
            for (int nt = 0; nt < 8; ++nt) {
                float ha  = bf16_to_f((unsigned short)hav[r][nt]);
                float hb  = bf16_to_f((unsigned short)hbv[r][nt]);
                float pre = acc[mt][nt][r] + ha + hb;
                float el  = pre > 0.f ? pre : expm1f(pre);
                sr = fmaf(el, w2v[nt], sr);
            }
            if (r == 0) s0 = sr; else if (r == 1) s1 = sr; else if (r == 2) s2 = sr; else s3 = sr;
        }
        // reduce over the 16 lm-lanes of each quad group (xor masks 1,2,4,8)
#pragma unroll
        for (int m = 1; m < 16; m <<= 1) {
            s0 += __shfl_xor(s0, m, 64);
            s1 += __shfl_xor(s1, m, 64);
            s2 += __shfl_xor(s2, m, 64);
            s3 += __shfl_xor(s3, m, 64);
        }
        if (lm < 4) {
            float sum = (lm == 0) ? s0 : (lm == 1) ? s1 : (lm == 2) ? s2 : s3;
            sum += b2s;
            float av = sum >= 0.f ? sum : 0.2f * sum;
            a_out[e4 + lm] = av;
        }
    }
}

// ---------------------------------------------------------------------------
// CSR build: histogram -> 3-phase scan -> scatter (+ col stream)
// ---------------------------------------------------------------------------
__global__ void k_hist(const int* __restrict__ eidx, int* __restrict__ hist)
{
    int e = blockIdx.x * 256 + threadIdx.x;
    if (e < NEDGES) atomicAdd(&hist[eidx[e]], 1);
}

__global__ void k_scan_blk(const int* __restrict__ hist, int* __restrict__ offsets,
                           int* __restrict__ bsum)
{
    __shared__ int sd[256];
    int t = threadIdx.x, i = blockIdx.x * 256 + t;
    int v = (i < NNODES) ? hist[i] : 0;
    sd[t] = v; __syncthreads();
    for (int off = 1; off < 256; off <<= 1) {
        int add = (t >= off) ? sd[t - off] : 0;
        __syncthreads();
        sd[t] += add;
        __syncthreads();
    }
    if (i < NNODES) offsets[i] = sd[t] - v;
    if (t == 255) bsum[blockIdx.x] = sd[255];
}

__global__ void k_scan_top(const int* __restrict__ bsum, int* __restrict__ bpre,
                           int* __restrict__ offsets)
{
    __shared__ int sd[256];
    int t = threadIdx.x;
    int v = (t < NB_SCAN) ? bsum[t] : 0;
    sd[t] = v; __syncthreads();
    for (int off = 1; off < 256; off <<= 1) {
        int add = (t >= off) ? sd[t - off] : 0;
        __syncthreads();
        sd[t] += add;
        __syncthreads();
    }
    if (t < NB_SCAN) bpre[t] = sd[t] - v;
    if (t == 255) offsets[NNODES] = sd[255];
}

__global__ void k_scan_add(int* __restrict__ offsets, const int* __restrict__ bpre)
{
    int i = blockIdx.x * 256 + threadIdx.x;
    if (i < NNODES) offsets[i] += bpre[i >> 8];
}

__global__ void k_scatter(const int* __restrict__ eidx, const int* __restrict__ offsets,
                          int* __restrict__ cursor, int* __restrict__ sorted,
                          int* __restrict__ col_s)
{
    int e = blockIdx.x * 256 + threadIdx.x;
    if (e < NEDGES) {
        int r   = eidx[e];
        int pos = offsets[r] + atomicAdd(&cursor[r], 1);
        sorted[pos] = e;
        col_s[pos]  = eidx[NEDGES + e];
    }
}

// ---------------------------------------------------------------------------
// Softmax reductions
// ---------------------------------------------------------------------------
__global__ void k_rmax1(const float* __restrict__ a, float* __restrict__ partial)
{
    __shared__ float s[256];
    int tid = threadIdx.x;
    float m = -INFINITY;
    for (int i = blockIdx.x * 256 + tid; i < NEDGES; i += gridDim.x * 256)
        m = fmaxf(m, a[i]);
    s[tid] = m; __syncthreads();
    for (int off = 128; off > 0; off >>= 1) {
        if (tid < off) s[tid] = fmaxf(s[tid], s[tid + off]);
        __syncthreads();
    }
    if (tid == 0) partial[blockIdx.x] = s[0];
}

__global__ void k_rmax2(const float* __restrict__ partial, float* __restrict__ mz)
{
    __shared__ float s[256];
    int tid = threadIdx.x;
    float m = -INFINITY;
    for (int i = tid; i < 1024; i += 256) m = fmaxf(m, partial[i]);
    s[tid] = m; __syncthreads();
    for (int off = 128; off > 0; off >>= 1) {
        if (tid < off) s[tid] = fmaxf(s[tid], s[tid + off]);
        __syncthreads();
    }
    if (tid == 0) mz[0] = s[0];
}

__global__ void k_rsum1(const float* __restrict__ a, const float* __restrict__ mz,
                        float* __restrict__ partial)
{
    __shared__ float s[256];
    int tid = threadIdx.x;
    float M = mz[0];
    float acc = 0.0f;
    for (int i = blockIdx.x * 256 + tid; i < NEDGES; i += gridDim.x * 256)
        acc += expf(a[i] - M);
    s[tid] = acc; __syncthreads();
    for (int off = 128; off > 0; off >>= 1) {
        if (tid < off) s[tid] += s[tid + off];
        __syncthreads();
    }
    if (tid == 0) partial[blockIdx.x] = s[0];
}

__global__ void k_rsum2(const float* __restrict__ partial, float* __restrict__ mz)
{
    __shared__ float s[256];
    int tid = threadIdx.x;
    float acc = 0.0f;
    for (int i = tid; i < 1024; i += 256) acc += partial[i];
    s[tid] = acc; __syncthreads();
    for (int off = 128; off > 0; off >>= 1) {
        if (tid < off) s[tid] += s[tid + off];
        __syncthreads();
    }
    if (tid == 0) mz[1] = 1.0f / s[0];
}

// alpha_sorted in-place over `sorted`: reads sorted[i] (edge id), overwrites
// the slot with alpha as float.
__global__ void k_alpha(const float* __restrict__ a, const float* __restrict__ mz,
                        int* __restrict__ sorted_alpha)
{
    int i = blockIdx.x * 256 + threadIdx.x;
    if (i < NEDGES) {
        int e = sorted_alpha[i];
        float al = expf(a[e] - mz[0]) * mz[1];
        ((float*)sorted_alpha)[i] = al;
    }
}

// ---------------------------------------------------------------------------
// Aggregation: one wave per node; alpha/col are contiguous streams, only the
// h[col] read is a gather (inherent to the algorithm). Unrolled x4 so four
// independent 8 B gathers are in flight per lane (was 1 -> latency-bound).
// FP accumulation order identical to the serial loop.
// ---------------------------------------------------------------------------
__global__ __launch_bounds__(256) void k_agg(
    const float* __restrict__ h, const float* __restrict__ alpha_s,
    const int* __restrict__ col_s, const int* __restrict__ offsets,
    float* __restrict__ out)
{
    int node = blockIdx.x * 4 + (threadIdx.x >> 6);
    int lane = threadIdx.x & 63;
    if (node >= NNODES) return;
    int s0 = offsets[node], s1 = offsets[node + 1];
    float2 acc = make_float2(0.0f, 0.0f);
    int i = s0;
    for (; i + 4 <= s1; i += 4) {
        int   c0 = col_s[i + 0], c1 = col_s[i + 1], c2 = col_s[i + 2], c3 = col_s[i + 3];
        float a0 = alpha_s[i + 0], a1 = alpha_s[i + 1], a2 = alpha_s[i + 2], a3 = alpha_s[i + 3];
        float2 h0 = *(const float2*)(h + (size_t)c0 * 128 + lane * 2);
        float2 h1 = *(const float2*)(h + (size_t)c1 * 128 + lane * 2);
        float2 h2 = *(const float2*)(h + (size_t)c2 * 128 + lane * 2);
        float2 h3 = *(const float2*)(h + (size_t)c3 * 128 + lane * 2);
        acc.x = fmaf(a0, h0.x, acc.x); acc.y = fmaf(a0, h0.y, acc.y);
        acc.x = fmaf(a1, h1.x, acc.x); acc.y = fmaf(a1, h1.y, acc.y);
        acc.x = fmaf(a2, h2.x, acc.x); acc.y = fmaf(a2, h2.y, acc.y);
        acc.x = fmaf(a3, h3.x, acc.x); acc.y = fmaf(a3, h3.y, acc.y);
    }
    for (; i < s1; ++i) {
        float al = alpha_s[i];
        int   cj = col_s[i];
        float2 hj = *(const float2*)(h + (size_t)cj * 128 + lane * 2);
        acc.x = fmaf(al, hj.x, acc.x);
        acc.y = fmaf(al, hj.y, acc.y);
    }
    *(float2*)(out + (size_t)node * 128 + lane * 2) = acc;
}

// ---------------------------------------------------------------------------
extern "C" void kernel_launch(void* const* d_in, const int* in_sizes, int n_in,
                              void* d_out, int out_size, void* d_ws, size_t ws_size,
                              hipStream_t stream)
{
    const float* h    = (const float*)d_in[0];
    const int*   eidx = (const int*)d_in[1];
    const float* ea   = (const float*)d_in[2];
    const float* W1   = (const float*)d_in[3];
    const float* b1   = (const float*)d_in[4];
    const float* W2   = (const float*)d_in[5];
    const float* b2   = (const float*)d_in[6];
    float* out = (float*)d_out;

    char* ws = (char*)d_ws;
    unsigned short* Hab = (unsigned short*)(ws);       // 25,600,000
    float* a_arr   = (float*)(ws + 25600000);          // 3,200,000
    int*   sorted  = (int*)  (ws + 28800000);          // 3,200,000 (becomes alpha_s)
    int*   col_s   = (int*)  (ws + 32000000);          // 3,200,000
    int*   offsets = (int*)  (ws + 35200000);          // 200,004 (padded)
    int*   cursor  = (int*)  (ws + 35400192);          // 200,000 (histogram too)
    float* pmax    = (float*)(ws + 35600384);          // 4096
    float* psum    = (float*)(ws + 35604480);          // 4096
    float* mz      = (float*)(ws + 35608576);          // 8
    int*   bsum    = (int*)  (ws + 35608640);          // 784 (pad 1024)
    int*   bpre    = (int*)  (ws + 35609664);          // 784 (pad 1024)
    unsigned short* Wt = (unsigned short*)(ws + 35610688); // 32,768

    hipMemsetAsync(cursor, 0, NNODES * sizeof(int), stream);

    k_prep<<<1, 256, 0, stream>>>(W1, Wt);
    k_gemm_node<<<dim3((NNODES + 127) / 128, 2), 256, 0, stream>>>(h, W1, b1, Hab);

    k_hist<<<(NEDGES + 255) / 256, 256, 0, stream>>>(eidx, cursor);
    k_scan_blk<<<NB_SCAN, 256, 0, stream>>>(cursor, offsets, bsum);
    k_scan_top<<<1, 256, 0, stream>>>(bsum, bpre, offsets);
    k_scan_add<<<NB_SCAN, 256, 0, stream>>>(offsets, bpre);
    hipMemsetAsync(cursor, 0, NNODES * sizeof(int), stream);
    k_scatter<<<(NEDGES + 255) / 256, 256, 0, stream>>>(eidx, offsets, cursor, sorted, col_s);

    k_edge_mfma<<<NEDGES / 128, 256, 0, stream>>>(ea, eidx, Wt, W2, b2, Hab, a_arr);

    k_rmax1<<<1024, 256, 0, stream>>>(a_arr, pmax);
    k_rmax2<<<1, 256, 0, stream>>>(pmax, mz);
    k_rsum1<<<1024, 256, 0, stream>>>(a_arr, mz, psum);
    k_rsum2<<<1, 256, 0, stream>>>(psum, mz);

    k_alpha<<<(NEDGES + 255) / 256, 256, 0, stream>>>(a_arr, mz, sorted);
    k_agg<<<(NNODES + 3) / 4, 256, 0, stream>>>(h, (const float*)sorted, col_s, offsets, out);
}

// Round 3
// 876.235 us; speedup vs baseline: 1.3194x; 1.1058x over previous
//
#include <hip/hip_runtime.h>
#include <hip/hip_bf16.h>
#include <math.h>

#define NNODES 50000
#define NEDGES 800000
#define HID    128
#define NB_SCAN 196    // ceil(50000/256)
#define NB_EDGE 6250   // NEDGES/128

typedef short bf16x8 __attribute__((ext_vector_type(8)));
typedef float f32x4  __attribute__((ext_vector_type(4)));

__device__ __forceinline__ unsigned short bf16_rn(float x) {
    union { float f; unsigned int u; } v; v.f = x;
    unsigned int r = v.u + 0x7fffu + ((v.u >> 16) & 1u);
    return (unsigned short)(r >> 16);
}
__device__ __forceinline__ float bf16_to_f(unsigned short u) {
    union { unsigned int u; float f; } v; v.u = ((unsigned int)u) << 16;
    return v.f;
}

// ---------------------------------------------------------------------------
// K0: transpose Wc (=W1[256:384]) into Wt[c][k] bf16 (32 KB, L2/L1 resident)
// ---------------------------------------------------------------------------
__global__ void k_prep(const float* __restrict__ W1, unsigned short* __restrict__ Wt)
{
    const float* Wc = W1 + 256 * 128;
    int base = (blockIdx.x * 256 + threadIdx.x) * 4;
#pragma unroll
    for (int i = 0; i < 4; ++i) {
        int idx = base + i;
        int c = idx >> 7, k = idx & 127;
        Wt[c * 128 + k] = bf16_rn(Wc[k * 128 + c]);
    }
}

// ---------------------------------------------------------------------------
// K1: node GEMM -> Hab bf16.  c<128: (h@Wa)[n][c]+b1[c];  c>=128: (h@Wb)[n][c-128]
// NUMERICS: bf16_rn bit-trick (proven 2.38e-7); do NOT substitute cvt_pk asm.
// ---------------------------------------------------------------------------
__global__ __launch_bounds__(256) void k_gemm_node(
    const float* __restrict__ h, const float* __restrict__ W1,
    const float* __restrict__ b1, unsigned short* __restrict__ Hab)
{
    __shared__ float at[32][132];
    __shared__ float bt[32][128];

    const int tid = threadIdx.x;
    const int tx  = tid & 15;
    const int ty  = tid >> 4;
    const int nb  = blockIdx.x * 128;
    const int by  = blockIdx.y;
    const float* W = W1 + by * 128 * 128;

    float acc[8][8];
#pragma unroll
    for (int j = 0; j < 8; ++j)
#pragma unroll
        for (int c = 0; c < 8; ++c) acc[j][c] = 0.0f;

    for (int ks = 0; ks < 128; ks += 32) {
#pragma unroll
        for (int p = 0; p < 16; ++p) {
            int i  = (tid >> 5) + p * 8;
            int kk = tid & 31;
            int n  = nb + i;
            at[kk][i] = (n < NNODES) ? h[n * 128 + ks + kk] : 0.0f;
        }
#pragma unroll
        for (int p = 0; p < 16; ++p) {
            int kk = (tid >> 7) + p * 2;
            int c  = tid & 127;
            bt[kk][c] = W[(ks + kk) * 128 + c];
        }
        __syncthreads();
#pragma unroll
        for (int k = 0; k < 32; ++k) {
            float av[8], bv[8];
            *(float4*)&av[0] = *(const float4*)&at[k][ty * 8];
            *(float4*)&av[4] = *(const float4*)&at[k][ty * 8 + 4];
            *(float4*)&bv[0] = *(const float4*)&bt[k][tx * 8];
            *(float4*)&bv[4] = *(const float4*)&bt[k][tx * 8 + 4];
#pragma unroll
            for (int j = 0; j < 8; ++j)
#pragma unroll
                for (int c = 0; c < 8; ++c)
                    acc[j][c] = fmaf(av[j], bv[c], acc[j][c]);
        }
        __syncthreads();
    }

    float b1v[8];
    if (by == 0) {
        *(float4*)&b1v[0] = *(const float4*)&b1[tx * 8];
        *(float4*)&b1v[4] = *(const float4*)&b1[tx * 8 + 4];
    } else {
#pragma unroll
        for (int c = 0; c < 8; ++c) b1v[c] = 0.0f;
    }
#pragma unroll
    for (int j = 0; j < 8; ++j) {
        int n = nb + ty * 8 + j;
        if (n < NNODES) {
            unsigned short o[8];
#pragma unroll
            for (int c = 0; c < 8; ++c) o[c] = bf16_rn(acc[j][c] + b1v[c]);
            unsigned short* dst = Hab + (size_t)n * 256 + by * 128 + tx * 8;
            *(int4*)dst = *(int4*)&o[0];
        }
    }
}

// ---------------------------------------------------------------------------
// K2: edge GEMM via bf16 MFMA, zero LDS staging.
// Fused: row histogram (lm==0 lanes), per-block softmax partials (m_b, sum_b).
// Channel permutation: (nt,lm) -> channel lm*8+nt so Hab/W2 per-lane access is
// contiguous (one bf16x8). 1-deep software pipeline on raw ea loads.
// NUMERICS identical to R1: bf16_rn conversion, expm1f ELU, expf partials.
// C/D layout: col=lane&15 (channel), row=quad*4+reg (edge).
// ---------------------------------------------------------------------------
__global__ __launch_bounds__(256) void k_edge_mfma(
    const float* __restrict__ ea, const int* __restrict__ eidx,
    const unsigned short* __restrict__ Wt, const float* __restrict__ W2,
    const float* __restrict__ b2, const unsigned short* __restrict__ Hab,
    float* __restrict__ a_out, int* __restrict__ hist,
    float* __restrict__ bmax, float* __restrict__ bsumE)
{
    const int tid  = threadIdx.x;
    const int w    = tid >> 6;
    const int l    = tid & 63;
    const int quad = l >> 4;
    const int lm   = l & 15;
    const int wm   = w * 32;                 // 32 edges per wave
    const int ebase = blockIdx.x * 128;

    __shared__ float sred[8];

    f32x4 acc[2][8] = {};

    // hoist edge-index loads: in flight during the MFMA stages
    int rows0[4], cols0[4], rows1[4], cols1[4];
    {
        const int e40 = ebase + wm + quad * 4;
        const int e41 = e40 + 16;
#pragma unroll
        for (int r = 0; r < 4; ++r) {
            rows0[r] = eidx[e40 + r];
            cols0[r] = eidx[NEDGES + e40 + r];
            rows1[r] = eidx[e41 + r];
            cols1[r] = eidx[NEDGES + e41 + r];
        }
    }
    // fused histogram: each edge counted exactly once (lm==0 lane of its quad)
    if (lm == 0) {
#pragma unroll
        for (int r = 0; r < 4; ++r) {
            atomicAdd(&hist[rows0[r]], 1);
            atomicAdd(&hist[rows1[r]], 1);
        }
    }

    // software pipeline: next stage's raw ea (64 B/thread) in flight under MFMA
    const float* abase0 = ea + (size_t)(ebase + wm + lm) * 128 + quad * 8;
    const float* abase1 = abase0 + 16 * 128;
    float4 raw[2][2][2];
    raw[0][0][0] = *(const float4*)(abase0);
    raw[0][0][1] = *(const float4*)(abase0 + 4);
    raw[0][1][0] = *(const float4*)(abase1);
    raw[0][1][1] = *(const float4*)(abase1 + 4);

#pragma unroll
    for (int stage = 0; stage < 4; ++stage) {
        const int ks  = stage * 32;
        const int cur = stage & 1, nxt = cur ^ 1;
        if (stage < 3) {
            const int ko = ks + 32;
            raw[nxt][0][0] = *(const float4*)(abase0 + ko);
            raw[nxt][0][1] = *(const float4*)(abase0 + ko + 4);
            raw[nxt][1][0] = *(const float4*)(abase1 + ko);
            raw[nxt][1][1] = *(const float4*)(abase1 + ko + 4);
        }
        bf16x8 bfrag[8];
#pragma unroll
        for (int nt = 0; nt < 8; ++nt) {
            const unsigned short* bp = Wt + (lm * 8 + nt) * 128 + ks + quad * 8;
            bfrag[nt] = *(const bf16x8*)bp;
        }
        bf16x8 afrag[2];
#pragma unroll
        for (int mt = 0; mt < 2; ++mt) {
            float4 x0 = raw[cur][mt][0];
            float4 x1 = raw[cur][mt][1];
            bf16x8 f;
            f[0] = (short)bf16_rn(x0.x); f[1] = (short)bf16_rn(x0.y);
            f[2] = (short)bf16_rn(x0.z); f[3] = (short)bf16_rn(x0.w);
            f[4] = (short)bf16_rn(x1.x); f[5] = (short)bf16_rn(x1.y);
            f[6] = (short)bf16_rn(x1.z); f[7] = (short)bf16_rn(x1.w);
            afrag[mt] = f;
        }
#pragma unroll
        for (int mt = 0; mt < 2; ++mt)
#pragma unroll
            for (int nt = 0; nt < 8; ++nt)
                acc[mt][nt] = __builtin_amdgcn_mfma_f32_16x16x32_bf16(
                    afrag[mt], bfrag[nt], acc[mt][nt], 0, 0, 0);
    }

    // epilogue: pre[c] = acc + Ha[row][c] + Hb[col][c]; elu (expm1f); dot W2
    float w2v[8];
    *(float4*)&w2v[0] = *(const float4*)&W2[lm * 8];
    *(float4*)&w2v[4] = *(const float4*)&W2[lm * 8 + 4];
    const float b2s = b2[0];

    float avl[2] = { -INFINITY, -INFINITY };

#pragma unroll
    for (int mt = 0; mt < 2; ++mt) {
        const int e4 = ebase + wm + mt * 16 + quad * 4;   // 4 edges of this quad

        bf16x8 hav[4], hbv[4];
#pragma unroll
        for (int r = 0; r < 4; ++r) {
            int row  = (mt == 0) ? rows0[r] : rows1[r];
            int colj = (mt == 0) ? cols0[r] : cols1[r];
            hav[r] = *(const bf16x8*)(Hab + (size_t)row  * 256 + lm * 8);
            hbv[r] = *(const bf16x8*)(Hab + (size_t)colj * 256 + 128 + lm * 8);
        }

        float s0 = 0.f, s1 = 0.f, s2 = 0.f, s3 = 0.f;
#pragma unroll
        for (int r = 0; r < 4; ++r) {
            float sr = 0.f;
#pragma unroll
            for (int nt = 0; nt < 8; ++nt) {
                float ha  = bf16_to_f((unsigned short)hav[r][nt]);
                float hb  = bf16_to_f((unsigned short)hbv[r][nt]);
                float pre = acc[mt][nt][r] + ha + hb;
                float el  = pre > 0.f ? pre : expm1f(pre);
                sr = fmaf(el, w2v[nt], sr);
            }
            if (r == 0) s0 = sr; else if (r == 1) s1 = sr; else if (r == 2) s2 = sr; else s3 = sr;
        }
#pragma unroll
        for (int m = 1; m < 16; m <<= 1) {
            s0 += __shfl_xor(s0, m, 64);
            s1 += __shfl_xor(s1, m, 64);
            s2 += __shfl_xor(s2, m, 64);
            s3 += __shfl_xor(s3, m, 64);
        }
        if (lm < 4) {
            float sum = (lm == 0) ? s0 : (lm == 1) ? s1 : (lm == 2) ? s2 : s3;
            sum += b2s;
            float av = sum >= 0.f ? sum : 0.2f * sum;
            a_out[e4 + lm] = av;
            avl[mt] = av;
        }
    }

    // fused per-block softmax partials: m_b and sum_b = sum expf(a - m_b).
    // M = max_b(m_b) is EXACT; S reassociation error is a uniform alpha scale
    // (~1 ulp) -> negligible on output. expf (libm) for accuracy.
    float m = fmaxf(avl[0], avl[1]);
#pragma unroll
    for (int msk = 1; msk < 64; msk <<= 1) m = fmaxf(m, __shfl_xor(m, msk, 64));
    if (l == 0) sred[w] = m;
    __syncthreads();
    float mb = fmaxf(fmaxf(sred[0], sred[1]), fmaxf(sred[2], sred[3]));
    float es = 0.f;
    if (avl[0] > -INFINITY)
        es = expf(avl[0] - mb) + expf(avl[1] - mb);
#pragma unroll
    for (int msk = 1; msk < 64; msk <<= 1) es += __shfl_xor(es, msk, 64);
    if (l == 0) sred[4 + w] = es;
    __syncthreads();
    if (tid == 0) {
        bmax[blockIdx.x]  = mb;
        bsumE[blockIdx.x] = sred[4] + sred[5] + sred[6] + sred[7];
    }
}

// ---------------------------------------------------------------------------
// CSR build: (hist fused in k_edge) -> 3-phase scan -> scatter of (edge,col)
// ---------------------------------------------------------------------------
__global__ void k_scan_blk(const int* __restrict__ hist, int* __restrict__ offsets,
                           int* __restrict__ bsum)
{
    __shared__ int sd[256];
    int t = threadIdx.x, i = blockIdx.x * 256 + t;
    int v = (i < NNODES) ? hist[i] : 0;
    sd[t] = v; __syncthreads();
    for (int off = 1; off < 256; off <<= 1) {
        int add = (t >= off) ? sd[t - off] : 0;
        __syncthreads();
        sd[t] += add;
        __syncthreads();
    }
    if (i < NNODES) offsets[i] = sd[t] - v;
    if (t == 255) bsum[blockIdx.x] = sd[255];
}

__global__ void k_scan_top(const int* __restrict__ bsum, int* __restrict__ bpre,
                           int* __restrict__ offsets)
{
    __shared__ int sd[256];
    int t = threadIdx.x;
    int v = (t < NB_SCAN) ? bsum[t] : 0;
    sd[t] = v; __syncthreads();
    for (int off = 1; off < 256; off <<= 1) {
        int add = (t >= off) ? sd[t - off] : 0;
        __syncthreads();
        sd[t] += add;
        __syncthreads();
    }
    if (t < NB_SCAN) bpre[t] = sd[t] - v;
    if (t == 255) offsets[NNODES] = sd[255];
}

__global__ void k_scan_add(int* __restrict__ offsets, const int* __restrict__ bpre)
{
    int i = blockIdx.x * 256 + threadIdx.x;
    if (i < NNODES) offsets[i] += bpre[i >> 8];
}

__global__ void k_scatter(const int* __restrict__ eidx, const int* __restrict__ offsets,
                          int* __restrict__ cursor, int2* __restrict__ pairs)
{
    int e = blockIdx.x * 256 + threadIdx.x;
    if (e < NEDGES) {
        int r   = eidx[e];
        int pos = offsets[r] + atomicAdd(&cursor[r], 1);
        pairs[pos] = make_int2(e, eidx[NEDGES + e]);
    }
}

// ---------------------------------------------------------------------------
// Softmax final: combine 6250 per-block (m_b, sum_b) -> M, 1/S
// ---------------------------------------------------------------------------
__global__ __launch_bounds__(1024) void k_final(
    const float* __restrict__ bmax, const float* __restrict__ bsumE,
    float* __restrict__ mz)
{
    __shared__ float sd[1024];
    int tid = threadIdx.x;
    float m = -INFINITY;
    for (int i = tid; i < NB_EDGE; i += 1024) m = fmaxf(m, bmax[i]);
    sd[tid] = m; __syncthreads();
    for (int off = 512; off > 0; off >>= 1) {
        if (tid < off) sd[tid] = fmaxf(sd[tid], sd[tid + off]);
        __syncthreads();
    }
    float M = sd[0];
    __syncthreads();
    float s = 0.f;
    for (int i = tid; i < NB_EDGE; i += 1024) s += bsumE[i] * expf(bmax[i] - M);
    sd[tid] = s; __syncthreads();
    for (int off = 512; off > 0; off >>= 1) {
        if (tid < off) sd[tid] += sd[tid + off];
        __syncthreads();
    }
    if (tid == 0) { mz[0] = M; mz[1] = 1.0f / sd[0]; }
}

// alpha in-place over pairs[].x: reads edge id, overwrites with alpha bits.
__global__ void k_alpha(const float* __restrict__ a, const float* __restrict__ mz,
                        int2* __restrict__ pairs)
{
    int i = blockIdx.x * 256 + threadIdx.x;
    if (i < NEDGES) {
        int2 p = pairs[i];
        float al = expf(a[p.x] - mz[0]) * mz[1];
        p.x = __float_as_int(al);
        pairs[i] = p;
    }
}

// ---------------------------------------------------------------------------
// Aggregation: one wave per node; single 8 B stream load per edge (alpha,col),
// unrolled x8 so 8 independent row-gathers are in flight per lane.
// FP accumulation order identical to the serial loop.
// ---------------------------------------------------------------------------
__global__ __launch_bounds__(256) void k_agg(
    const float* __restrict__ h, const int2* __restrict__ pairs,
    const int* __restrict__ offsets, float* __restrict__ out)
{
    int node = blockIdx.x * 4 + (threadIdx.x >> 6);
    int lane = threadIdx.x & 63;
    if (node >= NNODES) return;
    int s0 = offsets[node], s1 = offsets[node + 1];
    float2 acc = make_float2(0.0f, 0.0f);
    int i = s0;
    for (; i + 8 <= s1; i += 8) {
        int2 p[8];
#pragma unroll
        for (int r = 0; r < 8; ++r) p[r] = pairs[i + r];
        float2 hv[8];
#pragma unroll
        for (int r = 0; r < 8; ++r)
            hv[r] = *(const float2*)(h + (size_t)p[r].y * 128 + lane * 2);
#pragma unroll
        for (int r = 0; r < 8; ++r) {
            float al = __int_as_float(p[r].x);
            acc.x = fmaf(al, hv[r].x, acc.x);
            acc.y = fmaf(al, hv[r].y, acc.y);
        }
    }
    for (; i < s1; ++i) {
        int2 p = pairs[i];
        float al = __int_as_float(p.x);
        float2 hj = *(const float2*)(h + (size_t)p.y * 128 + lane * 2);
        acc.x = fmaf(al, hj.x, acc.x);
        acc.y = fmaf(al, hj.y, acc.y);
    }
    *(float2*)(out + (size_t)node * 128 + lane * 2) = acc;
}

// ---------------------------------------------------------------------------
extern "C" void kernel_launch(void* const* d_in, const int* in_sizes, int n_in,
                              void* d_out, int out_size, void* d_ws, size_t ws_size,
                              hipStream_t stream)
{
    const float* h    = (const float*)d_in[0];
    const int*   eidx = (const int*)d_in[1];
    const float* ea   = (const float*)d_in[2];
    const float* W1   = (const float*)d_in[3];
    const float* b1   = (const float*)d_in[4];
    const float* W2   = (const float*)d_in[5];
    const float* b2   = (const float*)d_in[6];
    float* out = (float*)d_out;

    char* ws = (char*)d_ws;
    unsigned short* Hab = (unsigned short*)(ws);       // 25,600,000
    float* a_arr   = (float*)(ws + 25600000);          // 3,200,000
    int2*  pairs   = (int2*) (ws + 28800000);          // 6,400,000 (edge,col) -> (alpha,col)
    int*   offsets = (int*)  (ws + 35200000);          // 200,004 (padded)
    int*   cursor  = (int*)  (ws + 35400192);          // 200,000 (histogram too)
    float* bmax    = (float*)(ws + 35600384);          // 25,000 (pad 25,600)
    float* bsumE   = (float*)(ws + 35625984);          // 25,000 (pad 25,600)
    float* mz      = (float*)(ws + 35651584);          // 64
    unsigned short* Wt = (unsigned short*)(ws + 35651648); // 32,768
    int*   bsum_s  = (int*)  (ws + 35684416);          // 784 (pad 1024)
    int*   bpre_s  = (int*)  (ws + 35685440);          // 784 (pad 1024)

    hipMemsetAsync(cursor, 0, NNODES * sizeof(int), stream);

    k_prep<<<16, 256, 0, stream>>>(W1, Wt);
    k_gemm_node<<<dim3((NNODES + 127) / 128, 2), 256, 0, stream>>>(h, W1, b1, Hab);

    // big edge kernel: GEMM + attention logits + fused histogram + block partials
    k_edge_mfma<<<NB_EDGE, 256, 0, stream>>>(ea, eidx, Wt, W2, b2, Hab,
                                             a_arr, cursor, bmax, bsumE);

    k_scan_blk<<<NB_SCAN, 256, 0, stream>>>(cursor, offsets, bsum_s);
    k_scan_top<<<1, 256, 0, stream>>>(bsum_s, bpre_s, offsets);
    k_scan_add<<<NB_SCAN, 256, 0, stream>>>(offsets, bpre_s);
    hipMemsetAsync(cursor, 0, NNODES * sizeof(int), stream);
    k_scatter<<<(NEDGES + 255) / 256, 256, 0, stream>>>(eidx, offsets, cursor, pairs);

    k_final<<<1, 1024, 0, stream>>>(bmax, bsumE, mz);
    k_alpha<<<(NEDGES + 255) / 256, 256, 0, stream>>>(a_arr, mz, pairs);
    k_agg<<<(NNODES + 3) / 4, 256, 0, stream>>>(h, pairs, offsets, out);
}

// Round 4
// 869.187 us; speedup vs baseline: 1.3301x; 1.0081x over previous
//
#include <hip/hip_runtime.h>
#include <hip/hip_bf16.h>
#include <math.h>

#define NNODES 50000
#define NEDGES 800000
#define HID    128
#define NB_SCAN 196    // ceil(50000/256)
#define NB_EDGE 6250   // NEDGES/128

typedef short bf16x8 __attribute__((ext_vector_type(8)));
typedef float f32x4  __attribute__((ext_vector_type(4)));

__device__ __forceinline__ unsigned short bf16_rn(float x) {
    union { float f; unsigned int u; } v; v.f = x;
    unsigned int r = v.u + 0x7fffu + ((v.u >> 16) & 1u);
    return (unsigned short)(r >> 16);
}
__device__ __forceinline__ float bf16_to_f(unsigned short u) {
    union { unsigned int u; float f; } v; v.u = ((unsigned int)u) << 16;
    return v.f;
}

// Branch-free expm1 for x<=0: 7-term Taylor on (-0.25,0] (trunc err <= 4e-10),
// __expf(x)-1 for x<=-0.25 (|expm1|>=0.221 -> no cancellation, rel err ~4e-7).
__device__ __forceinline__ float expm1_fast(float x) {
    float t = 1.9841270e-4f;               // 1/5040
    t = fmaf(t, x, 1.3888889e-3f);         // 1/720
    t = fmaf(t, x, 8.3333333e-3f);         // 1/120
    t = fmaf(t, x, 4.1666668e-2f);         // 1/24
    t = fmaf(t, x, 0.16666667f);           // 1/6
    t = fmaf(t, x, 0.5f);
    t = fmaf(t, x, 1.0f);
    float poly = x * t;
    float ex   = __expf(x) - 1.0f;
    return (x > -0.25f) ? poly : ex;
}

// ---------------------------------------------------------------------------
// K0: transpose Wc (=W1[256:384]) into Wt[c][k] bf16 (32 KB, L2/L1 resident)
// ---------------------------------------------------------------------------
__global__ void k_prep(const float* __restrict__ W1, unsigned short* __restrict__ Wt)
{
    const float* Wc = W1 + 256 * 128;
    int base = (blockIdx.x * 256 + threadIdx.x) * 4;
#pragma unroll
    for (int i = 0; i < 4; ++i) {
        int idx = base + i;
        int c = idx >> 7, k = idx & 127;
        Wt[c * 128 + k] = bf16_rn(Wc[k * 128 + c]);
    }
}

// ---------------------------------------------------------------------------
// K1: node GEMM -> Hab bf16.  c<128: (h@Wa)[n][c]+b1[c];  c>=128: (h@Wb)[n][c-128]
// NUMERICS: bf16_rn bit-trick (proven 2.38e-7); do NOT substitute cvt_pk asm.
// ---------------------------------------------------------------------------
__global__ __launch_bounds__(256) void k_gemm_node(
    const float* __restrict__ h, const float* __restrict__ W1,
    const float* __restrict__ b1, unsigned short* __restrict__ Hab)
{
    __shared__ float at[32][132];
    __shared__ float bt[32][128];

    const int tid = threadIdx.x;
    const int tx  = tid & 15;
    const int ty  = tid >> 4;
    const int nb  = blockIdx.x * 128;
    const int by  = blockIdx.y;
    const float* W = W1 + by * 128 * 128;

    float acc[8][8];
#pragma unroll
    for (int j = 0; j < 8; ++j)
#pragma unroll
        for (int c = 0; c < 8; ++c) acc[j][c] = 0.0f;

    for (int ks = 0; ks < 128; ks += 32) {
#pragma unroll
        for (int p = 0; p < 16; ++p) {
            int i  = (tid >> 5) + p * 8;
            int kk = tid & 31;
            int n  = nb + i;
            at[kk][i] = (n < NNODES) ? h[n * 128 + ks + kk] : 0.0f;
        }
#pragma unroll
        for (int p = 0; p < 16; ++p) {
            int kk = (tid >> 7) + p * 2;
            int c  = tid & 127;
            bt[kk][c] = W[(ks + kk) * 128 + c];
        }
        __syncthreads();
#pragma unroll
        for (int k = 0; k < 32; ++k) {
            float av[8], bv[8];
            *(float4*)&av[0] = *(const float4*)&at[k][ty * 8];
            *(float4*)&av[4] = *(const float4*)&at[k][ty * 8 + 4];
            *(float4*)&bv[0] = *(const float4*)&bt[k][tx * 8];
            *(float4*)&bv[4] = *(const float4*)&bt[k][tx * 8 + 4];
#pragma unroll
            for (int j = 0; j < 8; ++j)
#pragma unroll
                for (int c = 0; c < 8; ++c)
                    acc[j][c] = fmaf(av[j], bv[c], acc[j][c]);
        }
        __syncthreads();
    }

    float b1v[8];
    if (by == 0) {
        *(float4*)&b1v[0] = *(const float4*)&b1[tx * 8];
        *(float4*)&b1v[4] = *(const float4*)&b1[tx * 8 + 4];
    } else {
#pragma unroll
        for (int c = 0; c < 8; ++c) b1v[c] = 0.0f;
    }
#pragma unroll
    for (int j = 0; j < 8; ++j) {
        int n = nb + ty * 8 + j;
        if (n < NNODES) {
            unsigned short o[8];
#pragma unroll
            for (int c = 0; c < 8; ++c) o[c] = bf16_rn(acc[j][c] + b1v[c]);
            unsigned short* dst = Hab + (size_t)n * 256 + by * 128 + tx * 8;
            *(int4*)dst = *(int4*)&o[0];
        }
    }
}

// ---------------------------------------------------------------------------
// K2: edge GEMM via bf16 MFMA, zero LDS staging.
// Fused: row histogram (lm==0 lanes), per-block softmax partials (m_b, sum_b).
// Channel permutation: (nt,lm) -> channel lm*8+nt so Hab/W2 per-lane access is
// contiguous (one bf16x8). 1-deep software pipeline on raw ea loads.
// Hab gathers issued inside stage 3 so stage-3 cvt+MFMA hides their latency.
// ELU via expm1_fast (bounded |err| <= ~1e-7 on logits); partials use libm expf.
// C/D layout: col=lane&15 (channel), row=quad*4+reg (edge).
// ---------------------------------------------------------------------------
__global__ __launch_bounds__(256) void k_edge_mfma(
    const float* __restrict__ ea, const int* __restrict__ eidx,
    const unsigned short* __restrict__ Wt, const float* __restrict__ W2,
    const float* __restrict__ b2, const unsigned short* __restrict__ Hab,
    float* __restrict__ a_out, int* __restrict__ hist,
    float* __restrict__ bmax, float* __restrict__ bsumE)
{
    const int tid  = threadIdx.x;
    const int w    = tid >> 6;
    const int l    = tid & 63;
    const int quad = l >> 4;
    const int lm   = l & 15;
    const int wm   = w * 32;                 // 32 edges per wave
    const int ebase = blockIdx.x * 128;

    __shared__ float sred[8];

    f32x4 acc[2][8] = {};

    // hoist edge-index loads: in flight during the MFMA stages
    int rows0[4], cols0[4], rows1[4], cols1[4];
    {
        const int e40 = ebase + wm + quad * 4;
        const int e41 = e40 + 16;
#pragma unroll
        for (int r = 0; r < 4; ++r) {
            rows0[r] = eidx[e40 + r];
            cols0[r] = eidx[NEDGES + e40 + r];
            rows1[r] = eidx[e41 + r];
            cols1[r] = eidx[NEDGES + e41 + r];
        }
    }
    // fused histogram: each edge counted exactly once (lm==0 lane of its quad)
    if (lm == 0) {
#pragma unroll
        for (int r = 0; r < 4; ++r) {
            atomicAdd(&hist[rows0[r]], 1);
            atomicAdd(&hist[rows1[r]], 1);
        }
    }

    // software pipeline: next stage's raw ea (64 B/thread) in flight under MFMA
    const float* abase0 = ea + (size_t)(ebase + wm + lm) * 128 + quad * 8;
    const float* abase1 = abase0 + 16 * 128;
    float4 raw[2][2][2];
    raw[0][0][0] = *(const float4*)(abase0);
    raw[0][0][1] = *(const float4*)(abase0 + 4);
    raw[0][1][0] = *(const float4*)(abase1);
    raw[0][1][1] = *(const float4*)(abase1 + 4);

    bf16x8 hav[2][4], hbv[2][4];   // issued in stage 3, consumed in epilogue

#pragma unroll
    for (int stage = 0; stage < 4; ++stage) {
        const int ks  = stage * 32;
        const int cur = stage & 1, nxt = cur ^ 1;
        if (stage < 3) {
            const int ko = ks + 32;
            raw[nxt][0][0] = *(const float4*)(abase0 + ko);
            raw[nxt][0][1] = *(const float4*)(abase0 + ko + 4);
            raw[nxt][1][0] = *(const float4*)(abase1 + ko);
            raw[nxt][1][1] = *(const float4*)(abase1 + ko + 4);
        }
        if (stage == 3) {
            // issue Hab gathers now; stage-3 cvt + 16 MFMA cover their latency
#pragma unroll
            for (int r = 0; r < 4; ++r) {
                hav[0][r] = *(const bf16x8*)(Hab + (size_t)rows0[r] * 256 + lm * 8);
                hbv[0][r] = *(const bf16x8*)(Hab + (size_t)cols0[r] * 256 + 128 + lm * 8);
                hav[1][r] = *(const bf16x8*)(Hab + (size_t)rows1[r] * 256 + lm * 8);
                hbv[1][r] = *(const bf16x8*)(Hab + (size_t)cols1[r] * 256 + 128 + lm * 8);
            }
        }
        bf16x8 bfrag[8];
#pragma unroll
        for (int nt = 0; nt < 8; ++nt) {
            const unsigned short* bp = Wt + (lm * 8 + nt) * 128 + ks + quad * 8;
            bfrag[nt] = *(const bf16x8*)bp;
        }
        bf16x8 afrag[2];
#pragma unroll
        for (int mt = 0; mt < 2; ++mt) {
            float4 x0 = raw[cur][mt][0];
            float4 x1 = raw[cur][mt][1];
            bf16x8 f;
            f[0] = (short)bf16_rn(x0.x); f[1] = (short)bf16_rn(x0.y);
            f[2] = (short)bf16_rn(x0.z); f[3] = (short)bf16_rn(x0.w);
            f[4] = (short)bf16_rn(x1.x); f[5] = (short)bf16_rn(x1.y);
            f[6] = (short)bf16_rn(x1.z); f[7] = (short)bf16_rn(x1.w);
            afrag[mt] = f;
        }
#pragma unroll
        for (int mt = 0; mt < 2; ++mt)
#pragma unroll
            for (int nt = 0; nt < 8; ++nt)
                acc[mt][nt] = __builtin_amdgcn_mfma_f32_16x16x32_bf16(
                    afrag[mt], bfrag[nt], acc[mt][nt], 0, 0, 0);
    }

    // epilogue: pre[c] = acc + Ha[row][c] + Hb[col][c]; elu; dot W2
    float w2v[8];
    *(float4*)&w2v[0] = *(const float4*)&W2[lm * 8];
    *(float4*)&w2v[4] = *(const float4*)&W2[lm * 8 + 4];
    const float b2s = b2[0];

    float avl[2] = { -INFINITY, -INFINITY };

#pragma unroll
    for (int mt = 0; mt < 2; ++mt) {
        const int e4 = ebase + wm + mt * 16 + quad * 4;   // 4 edges of this quad

        float s0 = 0.f, s1 = 0.f, s2 = 0.f, s3 = 0.f;
#pragma unroll
        for (int r = 0; r < 4; ++r) {
            float sr = 0.f;
#pragma unroll
            for (int nt = 0; nt < 8; ++nt) {
                float ha  = bf16_to_f((unsigned short)hav[mt][r][nt]);
                float hb  = bf16_to_f((unsigned short)hbv[mt][r][nt]);
                float pre = acc[mt][nt][r] + ha + hb;
                float el  = pre > 0.f ? pre : expm1_fast(pre);
                sr = fmaf(el, w2v[nt], sr);
            }
            if (r == 0) s0 = sr; else if (r == 1) s1 = sr; else if (r == 2) s2 = sr; else s3 = sr;
        }
#pragma unroll
        for (int m = 1; m < 16; m <<= 1) {
            s0 += __shfl_xor(s0, m, 64);
            s1 += __shfl_xor(s1, m, 64);
            s2 += __shfl_xor(s2, m, 64);
            s3 += __shfl_xor(s3, m, 64);
        }
        if (lm < 4) {
            float sum = (lm == 0) ? s0 : (lm == 1) ? s1 : (lm == 2) ? s2 : s3;
            sum += b2s;
            float av = sum >= 0.f ? sum : 0.2f * sum;
            a_out[e4 + lm] = av;
            avl[mt] = av;
        }
    }

    // fused per-block softmax partials: m_b and sum_b = sum expf(a - m_b).
    // M = max_b(m_b) is EXACT; S reassociation error is a uniform alpha scale
    // (~1 ulp) -> negligible on output. expf (libm) for accuracy.
    float m = fmaxf(avl[0], avl[1]);
#pragma unroll
    for (int msk = 1; msk < 64; msk <<= 1) m = fmaxf(m, __shfl_xor(m, msk, 64));
    if (l == 0) sred[w] = m;
    __syncthreads();
    float mb = fmaxf(fmaxf(sred[0], sred[1]), fmaxf(sred[2], sred[3]));
    float es = 0.f;
    if (avl[0] > -INFINITY)
        es = expf(avl[0] - mb) + expf(avl[1] - mb);
#pragma unroll
    for (int msk = 1; msk < 64; msk <<= 1) es += __shfl_xor(es, msk, 64);
    if (l == 0) sred[4 + w] = es;
    __syncthreads();
    if (tid == 0) {
        bmax[blockIdx.x]  = mb;
        bsumE[blockIdx.x] = sred[4] + sred[5] + sred[6] + sred[7];
    }
}

// ---------------------------------------------------------------------------
// CSR build: (hist fused in k_edge) -> 3-phase scan -> scatter of (edge,col)
// ---------------------------------------------------------------------------
__global__ void k_scan_blk(const int* __restrict__ hist, int* __restrict__ offsets,
                           int* __restrict__ bsum)
{
    __shared__ int sd[256];
    int t = threadIdx.x, i = blockIdx.x * 256 + t;
    int v = (i < NNODES) ? hist[i] : 0;
    sd[t] = v; __syncthreads();
    for (int off = 1; off < 256; off <<= 1) {
        int add = (t >= off) ? sd[t - off] : 0;
        __syncthreads();
        sd[t] += add;
        __syncthreads();
    }
    if (i < NNODES) offsets[i] = sd[t] - v;
    if (t == 255) bsum[blockIdx.x] = sd[255];
}

__global__ void k_scan_top(const int* __restrict__ bsum, int* __restrict__ bpre,
                           int* __restrict__ offsets)
{
    __shared__ int sd[256];
    int t = threadIdx.x;
    int v = (t < NB_SCAN) ? bsum[t] : 0;
    sd[t] = v; __syncthreads();
    for (int off = 1; off < 256; off <<= 1) {
        int add = (t >= off) ? sd[t - off] : 0;
        __syncthreads();
        sd[t] += add;
        __syncthreads();
    }
    if (t < NB_SCAN) bpre[t] = sd[t] - v;
    if (t == 255) offsets[NNODES] = sd[255];
}

__global__ void k_scan_add(int* __restrict__ offsets, const int* __restrict__ bpre)
{
    int i = blockIdx.x * 256 + threadIdx.x;
    if (i < NNODES) offsets[i] += bpre[i >> 8];
}

__global__ void k_scatter(const int* __restrict__ eidx, const int* __restrict__ offsets,
                          int* __restrict__ cursor, int2* __restrict__ pairs)
{
    int e = blockIdx.x * 256 + threadIdx.x;
    if (e < NEDGES) {
        int r   = eidx[e];
        int pos = offsets[r] + atomicAdd(&cursor[r], 1);
        pairs[pos] = make_int2(e, eidx[NEDGES + e]);
    }
}

// ---------------------------------------------------------------------------
// Softmax final: combine 6250 per-block (m_b, sum_b) -> M, 1/S
// ---------------------------------------------------------------------------
__global__ __launch_bounds__(1024) void k_final(
    const float* __restrict__ bmax, const float* __restrict__ bsumE,
    float* __restrict__ mz)
{
    __shared__ float sd[1024];
    int tid = threadIdx.x;
    float m = -INFINITY;
    for (int i = tid; i < NB_EDGE; i += 1024) m = fmaxf(m, bmax[i]);
    sd[tid] = m; __syncthreads();
    for (int off = 512; off > 0; off >>= 1) {
        if (tid < off) sd[tid] = fmaxf(sd[tid], sd[tid + off]);
        __syncthreads();
    }
    float M = sd[0];
    __syncthreads();
    float s = 0.f;
    for (int i = tid; i < NB_EDGE; i += 1024) s += bsumE[i] * expf(bmax[i] - M);
    sd[tid] = s; __syncthreads();
    for (int off = 512; off > 0; off >>= 1) {
        if (tid < off) sd[tid] += sd[tid + off];
        __syncthreads();
    }
    if (tid == 0) { mz[0] = M; mz[1] = 1.0f / sd[0]; }
}

// ---------------------------------------------------------------------------
// Aggregation with fused alpha: pairs hold (edge, col); alpha computed inline
// as expf(a[e]-M)*invS (identical value & fma order to the old k_alpha+k_agg).
// One wave per node; 8 row-gathers in flight per lane.
// ---------------------------------------------------------------------------
__global__ __launch_bounds__(256) void k_agg(
    const float* __restrict__ h, const float* __restrict__ a,
    const int2* __restrict__ pairs, const int* __restrict__ offsets,
    const float* __restrict__ mz, float* __restrict__ out)
{
    int node = blockIdx.x * 4 + (threadIdx.x >> 6);
    int lane = threadIdx.x & 63;
    if (node >= NNODES) return;
    const float M    = mz[0];
    const float invS = mz[1];
    int s0 = offsets[node], s1 = offsets[node + 1];
    float2 acc = make_float2(0.0f, 0.0f);
    int i = s0;
    for (; i + 8 <= s1; i += 8) {
        int2 p[8];
#pragma unroll
        for (int r = 0; r < 8; ++r) p[r] = pairs[i + r];
        float av[8];
#pragma unroll
        for (int r = 0; r < 8; ++r) av[r] = a[p[r].x];
        float2 hv[8];
#pragma unroll
        for (int r = 0; r < 8; ++r)
            hv[r] = *(const float2*)(h + (size_t)p[r].y * 128 + lane * 2);
#pragma unroll
        for (int r = 0; r < 8; ++r) {
            float al = expf(av[r] - M) * invS;
            acc.x = fmaf(al, hv[r].x, acc.x);
            acc.y = fmaf(al, hv[r].y, acc.y);
        }
    }
    for (; i < s1; ++i) {
        int2 p = pairs[i];
        float al = expf(a[p.x] - M) * invS;
        float2 hj = *(const float2*)(h + (size_t)p.y * 128 + lane * 2);
        acc.x = fmaf(al, hj.x, acc.x);
        acc.y = fmaf(al, hj.y, acc.y);
    }
    *(float2*)(out + (size_t)node * 128 + lane * 2) = acc;
}

// ---------------------------------------------------------------------------
extern "C" void kernel_launch(void* const* d_in, const int* in_sizes, int n_in,
                              void* d_out, int out_size, void* d_ws, size_t ws_size,
                              hipStream_t stream)
{
    const float* h    = (const float*)d_in[0];
    const int*   eidx = (const int*)d_in[1];
    const float* ea   = (const float*)d_in[2];
    const float* W1   = (const float*)d_in[3];
    const float* b1   = (const float*)d_in[4];
    const float* W2   = (const float*)d_in[5];
    const float* b2   = (const float*)d_in[6];
    float* out = (float*)d_out;

    char* ws = (char*)d_ws;
    unsigned short* Hab = (unsigned short*)(ws);       // 25,600,000
    float* a_arr   = (float*)(ws + 25600000);          // 3,200,000
    int2*  pairs   = (int2*) (ws + 28800000);          // 6,400,000 (edge,col)
    int*   offsets = (int*)  (ws + 35200000);          // 200,004 (padded)
    int*   cursor  = (int*)  (ws + 35400192);          // 200,000 (histogram too)
    float* bmax    = (float*)(ws + 35600384);          // 25,000 (pad 25,600)
    float* bsumE   = (float*)(ws + 35625984);          // 25,000 (pad 25,600)
    float* mz      = (float*)(ws + 35651584);          // 64
    unsigned short* Wt = (unsigned short*)(ws + 35651648); // 32,768
    int*   bsum_s  = (int*)  (ws + 35684416);          // 784 (pad 1024)
    int*   bpre_s  = (int*)  (ws + 35685440);          // 784 (pad 1024)

    hipMemsetAsync(cursor, 0, NNODES * sizeof(int), stream);

    k_prep<<<16, 256, 0, stream>>>(W1, Wt);
    k_gemm_node<<<dim3((NNODES + 127) / 128, 2), 256, 0, stream>>>(h, W1, b1, Hab);

    // big edge kernel: GEMM + attention logits + fused histogram + block partials
    k_edge_mfma<<<NB_EDGE, 256, 0, stream>>>(ea, eidx, Wt, W2, b2, Hab,
                                             a_arr, cursor, bmax, bsumE);

    k_scan_blk<<<NB_SCAN, 256, 0, stream>>>(cursor, offsets, bsum_s);
    k_scan_top<<<1, 256, 0, stream>>>(bsum_s, bpre_s, offsets);
    k_scan_add<<<NB_SCAN, 256, 0, stream>>>(offsets, bpre_s);
    hipMemsetAsync(cursor, 0, NNODES * sizeof(int), stream);
    k_scatter<<<(NEDGES + 255) / 256, 256, 0, stream>>>(eidx, offsets, cursor, pairs);

    k_final<<<1, 1024, 0, stream>>>(bmax, bsumE, mz);
    k_agg<<<(NNODES + 3) / 4, 256, 0, stream>>>(h, a_arr, pairs, offsets, mz, out);
}

// Round 5
// 803.487 us; speedup vs baseline: 1.4389x; 1.0818x over previous
//
#include <hip/hip_runtime.h>
#include <hip/hip_bf16.h>
#include <math.h>

#define NNODES 50000
#define NEDGES 800000
#define HID    128
#define NB_SCAN 196    // ceil(50000/256)
#define NB_EDGE 6250   // NEDGES/128

typedef short bf16x8 __attribute__((ext_vector_type(8)));
typedef float f32x4  __attribute__((ext_vector_type(4)));

__device__ __forceinline__ unsigned short bf16_rn(float x) {
    union { float f; unsigned int u; } v; v.f = x;
    unsigned int r = v.u + 0x7fffu + ((v.u >> 16) & 1u);
    return (unsigned short)(r >> 16);
}
__device__ __forceinline__ float bf16_to_f(unsigned short u) {
    union { unsigned int u; float f; } v; v.u = ((unsigned int)u) << 16;
    return v.f;
}

// Branch-free expm1 for x<=0: 7-term Taylor on (-0.25,0] (trunc err <= 4e-10),
// __expf(x)-1 for x<=-0.25 (|expm1|>=0.221 -> no cancellation, rel err ~4e-7).
// R4-verified: absmax bit-identical to libm expm1f path.
__device__ __forceinline__ float expm1_fast(float x) {
    float t = 1.9841270e-4f;               // 1/5040
    t = fmaf(t, x, 1.3888889e-3f);         // 1/720
    t = fmaf(t, x, 8.3333333e-3f);         // 1/120
    t = fmaf(t, x, 4.1666668e-2f);         // 1/24
    t = fmaf(t, x, 0.16666667f);           // 1/6
    t = fmaf(t, x, 0.5f);
    t = fmaf(t, x, 1.0f);
    float poly = x * t;
    float ex   = __expf(x) - 1.0f;
    return (x > -0.25f) ? poly : ex;
}

// ---------------------------------------------------------------------------
// K0: transpose Wc (=W1[256:384]) into Wt[c][k] bf16 (32 KB, L2/L1 resident)
// ---------------------------------------------------------------------------
__global__ void k_prep(const float* __restrict__ W1, unsigned short* __restrict__ Wt)
{
    const float* Wc = W1 + 256 * 128;
    int base = (blockIdx.x * 256 + threadIdx.x) * 4;
#pragma unroll
    for (int i = 0; i < 4; ++i) {
        int idx = base + i;
        int c = idx >> 7, k = idx & 127;
        Wt[c * 128 + k] = bf16_rn(Wc[k * 128 + c]);
    }
}

// ---------------------------------------------------------------------------
// K1: node GEMM -> Hab bf16.  c<128: (h@Wa)[n][c]+b1[c];  c>=128: (h@Wb)[n][c-128]
// NUMERICS: bf16_rn bit-trick (proven 2.38e-7); do NOT substitute cvt_pk asm.
// ---------------------------------------------------------------------------
__global__ __launch_bounds__(256) void k_gemm_node(
    const float* __restrict__ h, const float* __restrict__ W1,
    const float* __restrict__ b1, unsigned short* __restrict__ Hab)
{
    __shared__ float at[32][132];
    __shared__ float bt[32][128];

    const int tid = threadIdx.x;
    const int tx  = tid & 15;
    const int ty  = tid >> 4;
    const int nb  = blockIdx.x * 128;
    const int by  = blockIdx.y;
    const float* W = W1 + by * 128 * 128;

    float acc[8][8];
#pragma unroll
    for (int j = 0; j < 8; ++j)
#pragma unroll
        for (int c = 0; c < 8; ++c) acc[j][c] = 0.0f;

    for (int ks = 0; ks < 128; ks += 32) {
#pragma unroll
        for (int p = 0; p < 16; ++p) {
            int i  = (tid >> 5) + p * 8;
            int kk = tid & 31;
            int n  = nb + i;
            at[kk][i] = (n < NNODES) ? h[n * 128 + ks + kk] : 0.0f;
        }
#pragma unroll
        for (int p = 0; p < 16; ++p) {
            int kk = (tid >> 7) + p * 2;
            int c  = tid & 127;
            bt[kk][c] = W[(ks + kk) * 128 + c];
        }
        __syncthreads();
#pragma unroll
        for (int k = 0; k < 32; ++k) {
            float av[8], bv[8];
            *(float4*)&av[0] = *(const float4*)&at[k][ty * 8];
            *(float4*)&av[4] = *(const float4*)&at[k][ty * 8 + 4];
            *(float4*)&bv[0] = *(const float4*)&bt[k][tx * 8];
            *(float4*)&bv[4] = *(const float4*)&bt[k][tx * 8 + 4];
#pragma unroll
            for (int j = 0; j < 8; ++j)
#pragma unroll
                for (int c = 0; c < 8; ++c)
                    acc[j][c] = fmaf(av[j], bv[c], acc[j][c]);
        }
        __syncthreads();
    }

    float b1v[8];
    if (by == 0) {
        *(float4*)&b1v[0] = *(const float4*)&b1[tx * 8];
        *(float4*)&b1v[4] = *(const float4*)&b1[tx * 8 + 4];
    } else {
#pragma unroll
        for (int c = 0; c < 8; ++c) b1v[c] = 0.0f;
    }
#pragma unroll
    for (int j = 0; j < 8; ++j) {
        int n = nb + ty * 8 + j;
        if (n < NNODES) {
            unsigned short o[8];
#pragma unroll
            for (int c = 0; c < 8; ++c) o[c] = bf16_rn(acc[j][c] + b1v[c]);
            unsigned short* dst = Hab + (size_t)n * 256 + by * 128 + tx * 8;
            *(int4*)dst = *(int4*)&o[0];
        }
    }
}

// ---------------------------------------------------------------------------
// K2: edge GEMM via bf16 MFMA.
// Wt staged in LDS with bijective XOR swizzle (byte ^= ((c>>3)&15)<<4):
// per quarter-wave, the 16 lanes' ds_read_b128 hit 16 distinct 16B slots ->
// conflict-free; removes 32 VMEM instrs/thread from the loop.
// eidx loaded as 4x int4. Hab gathers issued in stage 3 under MFMA.
// Fused: row histogram, per-block softmax partials. Values bit-identical to R4.
// ---------------------------------------------------------------------------
__global__ __launch_bounds__(256) void k_edge_mfma(
    const float* __restrict__ ea, const int* __restrict__ eidx,
    const unsigned short* __restrict__ Wt, const float* __restrict__ W2,
    const float* __restrict__ b2, const unsigned short* __restrict__ Hab,
    float* __restrict__ a_out, int* __restrict__ hist,
    float* __restrict__ bmax, float* __restrict__ bsumE)
{
    const int tid  = threadIdx.x;
    const int w    = tid >> 6;
    const int l    = tid & 63;
    const int quad = l >> 4;
    const int lm   = l & 15;
    const int wm   = w * 32;                 // 32 edges per wave
    const int ebase = blockIdx.x * 128;

    __shared__ __align__(16) unsigned short wlds[16384];  // 32 KB swizzled Wt
    __shared__ float sred[8];

    // stage Wt -> LDS (swizzled). byte = (c*256 + k*2) ^ (((c>>3)&15)<<4)
#pragma unroll
    for (int i = 0; i < 8; ++i) {
        int idx16 = i * 2048 + tid * 8;          // 8 shorts per store
        int c = idx16 >> 7;
        bf16x8 v = *(const bf16x8*)(Wt + idx16);
        int byte = (idx16 * 2) ^ (((c >> 3) & 15) << 4);
        *(bf16x8*)((char*)wlds + byte) = v;
    }

    f32x4 acc[2][8] = {};

    // edge-index loads: 4x int4 (e4 bases are multiples of 4 -> 16B aligned)
    int rows0[4], cols0[4], rows1[4], cols1[4];
    {
        const int e40 = ebase + wm + quad * 4;
        const int e41 = e40 + 16;
        int4 r0 = *(const int4*)(eidx + e40);
        int4 c0 = *(const int4*)(eidx + NEDGES + e40);
        int4 r1 = *(const int4*)(eidx + e41);
        int4 c1 = *(const int4*)(eidx + NEDGES + e41);
        rows0[0] = r0.x; rows0[1] = r0.y; rows0[2] = r0.z; rows0[3] = r0.w;
        cols0[0] = c0.x; cols0[1] = c0.y; cols0[2] = c0.z; cols0[3] = c0.w;
        rows1[0] = r1.x; rows1[1] = r1.y; rows1[2] = r1.z; rows1[3] = r1.w;
        cols1[0] = c1.x; cols1[1] = c1.y; cols1[2] = c1.z; cols1[3] = c1.w;
    }
    // fused histogram: each edge counted exactly once (lm==0 lane of its quad)
    if (lm == 0) {
#pragma unroll
        for (int r = 0; r < 4; ++r) {
            atomicAdd(&hist[rows0[r]], 1);
            atomicAdd(&hist[rows1[r]], 1);
        }
    }

    // software pipeline: next stage's raw ea (64 B/thread) in flight under MFMA
    const float* abase0 = ea + (size_t)(ebase + wm + lm) * 128 + quad * 8;
    const float* abase1 = abase0 + 16 * 128;
    float4 raw[2][2][2];
    raw[0][0][0] = *(const float4*)(abase0);
    raw[0][0][1] = *(const float4*)(abase0 + 4);
    raw[0][1][0] = *(const float4*)(abase1);
    raw[0][1][1] = *(const float4*)(abase1 + 4);

    bf16x8 hav[2][4], hbv[2][4];   // issued in stage 3, consumed in epilogue

    __syncthreads();               // wlds ready

#pragma unroll
    for (int stage = 0; stage < 4; ++stage) {
        const int ks  = stage * 32;
        const int cur = stage & 1, nxt = cur ^ 1;
        if (stage < 3) {
            const int ko = ks + 32;
            raw[nxt][0][0] = *(const float4*)(abase0 + ko);
            raw[nxt][0][1] = *(const float4*)(abase0 + ko + 4);
            raw[nxt][1][0] = *(const float4*)(abase1 + ko);
            raw[nxt][1][1] = *(const float4*)(abase1 + ko + 4);
        }
        if (stage == 3) {
            // issue Hab gathers now; stage-3 cvt + 16 MFMA cover their latency
#pragma unroll
            for (int r = 0; r < 4; ++r) {
                hav[0][r] = *(const bf16x8*)(Hab + (size_t)rows0[r] * 256 + lm * 8);
                hbv[0][r] = *(const bf16x8*)(Hab + (size_t)cols0[r] * 256 + 128 + lm * 8);
                hav[1][r] = *(const bf16x8*)(Hab + (size_t)rows1[r] * 256 + lm * 8);
                hbv[1][r] = *(const bf16x8*)(Hab + (size_t)cols1[r] * 256 + 128 + lm * 8);
            }
        }
        bf16x8 bfrag[8];
#pragma unroll
        for (int nt = 0; nt < 8; ++nt) {
            const int c = lm * 8 + nt;           // channel = lm*8+nt (permuted)
            const int byte = (c * 256 + (ks + quad * 8) * 2) ^ ((lm & 15) << 4);
            bfrag[nt] = *(const bf16x8*)((const char*)wlds + byte);
        }
        bf16x8 afrag[2];
#pragma unroll
        for (int mt = 0; mt < 2; ++mt) {
            float4 x0 = raw[cur][mt][0];
            float4 x1 = raw[cur][mt][1];
            bf16x8 f;
            f[0] = (short)bf16_rn(x0.x); f[1] = (short)bf16_rn(x0.y);
            f[2] = (short)bf16_rn(x0.z); f[3] = (short)bf16_rn(x0.w);
            f[4] = (short)bf16_rn(x1.x); f[5] = (short)bf16_rn(x1.y);
            f[6] = (short)bf16_rn(x1.z); f[7] = (short)bf16_rn(x1.w);
            afrag[mt] = f;
        }
#pragma unroll
        for (int mt = 0; mt < 2; ++mt)
#pragma unroll
            for (int nt = 0; nt < 8; ++nt)
                acc[mt][nt] = __builtin_amdgcn_mfma_f32_16x16x32_bf16(
                    afrag[mt], bfrag[nt], acc[mt][nt], 0, 0, 0);
    }

    // epilogue: pre[c] = acc + Ha[row][c] + Hb[col][c]; elu; dot W2
    float w2v[8];
    *(float4*)&w2v[0] = *(const float4*)&W2[lm * 8];
    *(float4*)&w2v[4] = *(const float4*)&W2[lm * 8 + 4];
    const float b2s = b2[0];

    float avl[2] = { -INFINITY, -INFINITY };

#pragma unroll
    for (int mt = 0; mt < 2; ++mt) {
        const int e4 = ebase + wm + mt * 16 + quad * 4;   // 4 edges of this quad

        float s0 = 0.f, s1 = 0.f, s2 = 0.f, s3 = 0.f;
#pragma unroll
        for (int r = 0; r < 4; ++r) {
            float sr = 0.f;
#pragma unroll
            for (int nt = 0; nt < 8; ++nt) {
                float ha  = bf16_to_f((unsigned short)hav[mt][r][nt]);
                float hb  = bf16_to_f((unsigned short)hbv[mt][r][nt]);
                float pre = acc[mt][nt][r] + ha + hb;
                float el  = pre > 0.f ? pre : expm1_fast(pre);
                sr = fmaf(el, w2v[nt], sr);
            }
            if (r == 0) s0 = sr; else if (r == 1) s1 = sr; else if (r == 2) s2 = sr; else s3 = sr;
        }
#pragma unroll
        for (int m = 1; m < 16; m <<= 1) {
            s0 += __shfl_xor(s0, m, 64);
            s1 += __shfl_xor(s1, m, 64);
            s2 += __shfl_xor(s2, m, 64);
            s3 += __shfl_xor(s3, m, 64);
        }
        if (lm < 4) {
            float sum = (lm == 0) ? s0 : (lm == 1) ? s1 : (lm == 2) ? s2 : s3;
            sum += b2s;
            float av = sum >= 0.f ? sum : 0.2f * sum;
            a_out[e4 + lm] = av;
            avl[mt] = av;
        }
    }

    // fused per-block softmax partials: m_b and sum_b = sum expf(a - m_b).
    float m = fmaxf(avl[0], avl[1]);
#pragma unroll
    for (int msk = 1; msk < 64; msk <<= 1) m = fmaxf(m, __shfl_xor(m, msk, 64));
    if (l == 0) sred[w] = m;
    __syncthreads();
    float mb = fmaxf(fmaxf(sred[0], sred[1]), fmaxf(sred[2], sred[3]));
    float es = 0.f;
    if (avl[0] > -INFINITY)
        es = expf(avl[0] - mb) + expf(avl[1] - mb);
#pragma unroll
    for (int msk = 1; msk < 64; msk <<= 1) es += __shfl_xor(es, msk, 64);
    if (l == 0) sred[4 + w] = es;
    __syncthreads();
    if (tid == 0) {
        bmax[blockIdx.x]  = mb;
        bsumE[blockIdx.x] = sred[4] + sred[5] + sred[6] + sred[7];
    }
}

// ---------------------------------------------------------------------------
// CSR build: (hist fused in k_edge) -> 3-phase scan -> scatter
// ---------------------------------------------------------------------------
__global__ void k_scan_blk(const int* __restrict__ hist, int* __restrict__ offsets,
                           int* __restrict__ bsum)
{
    __shared__ int sd[256];
    int t = threadIdx.x, i = blockIdx.x * 256 + t;
    int v = (i < NNODES) ? hist[i] : 0;
    sd[t] = v; __syncthreads();
    for (int off = 1; off < 256; off <<= 1) {
        int add = (t >= off) ? sd[t - off] : 0;
        __syncthreads();
        sd[t] += add;
        __syncthreads();
    }
    if (i < NNODES) offsets[i] = sd[t] - v;
    if (t == 255) bsum[blockIdx.x] = sd[255];
}

__global__ void k_scan_top(const int* __restrict__ bsum, int* __restrict__ bpre,
                           int* __restrict__ offsets)
{
    __shared__ int sd[256];
    int t = threadIdx.x;
    int v = (t < NB_SCAN) ? bsum[t] : 0;
    sd[t] = v; __syncthreads();
    for (int off = 1; off < 256; off <<= 1) {
        int add = (t >= off) ? sd[t - off] : 0;
        __syncthreads();
        sd[t] += add;
        __syncthreads();
    }
    if (t < NB_SCAN) bpre[t] = sd[t] - v;
    if (t == 255) offsets[NNODES] = sd[255];
}

__global__ void k_scan_add(int* __restrict__ offsets, const int* __restrict__ bpre)
{
    int i = blockIdx.x * 256 + threadIdx.x;
    if (i < NNODES) offsets[i] += bpre[i >> 8];
}

// ---------------------------------------------------------------------------
// Softmax final: combine 6250 per-block (m_b, sum_b) -> M, 1/S
// ---------------------------------------------------------------------------
__global__ __launch_bounds__(1024) void k_final(
    const float* __restrict__ bmax, const float* __restrict__ bsumE,
    float* __restrict__ mz)
{
    __shared__ float sd[1024];
    int tid = threadIdx.x;
    float m = -INFINITY;
    for (int i = tid; i < NB_EDGE; i += 1024) m = fmaxf(m, bmax[i]);
    sd[tid] = m; __syncthreads();
    for (int off = 512; off > 0; off >>= 1) {
        if (tid < off) sd[tid] = fmaxf(sd[tid], sd[tid + off]);
        __syncthreads();
    }
    float M = sd[0];
    __syncthreads();
    float s = 0.f;
    for (int i = tid; i < NB_EDGE; i += 1024) s += bsumE[i] * expf(bmax[i] - M);
    sd[tid] = s; __syncthreads();
    for (int off = 512; off > 0; off >>= 1) {
        if (tid < off) sd[tid] += sd[tid + off];
        __syncthreads();
    }
    if (tid == 0) { mz[0] = M; mz[1] = 1.0f / sd[0]; }
}

// ---------------------------------------------------------------------------
// Scatter with fused alpha: a[e] read is a COALESCED stream here (vs random
// gather if done later). alpha = expf(a[e]-M)*invS -- identical expression and
// order to the previous k_alpha. Stores (alpha_bits, col).
// ---------------------------------------------------------------------------
__global__ void k_scatter(const int* __restrict__ eidx, const int* __restrict__ offsets,
                          int* __restrict__ cursor, const float* __restrict__ a,
                          const float* __restrict__ mz, int2* __restrict__ pairs)
{
    int e = blockIdx.x * 256 + threadIdx.x;
    if (e < NEDGES) {
        int r    = eidx[e];
        float al = expf(a[e] - mz[0]) * mz[1];
        int pos  = offsets[r] + atomicAdd(&cursor[r], 1);
        pairs[pos] = make_int2(__float_as_int(al), eidx[NEDGES + e]);
    }
}

// ---------------------------------------------------------------------------
// Aggregation (R3-proven form): one wave per node; single 8 B stream load per
// edge (alpha,col); 8 independent h-row gathers in flight per lane.
// ---------------------------------------------------------------------------
__global__ __launch_bounds__(256) void k_agg(
    const float* __restrict__ h, const int2* __restrict__ pairs,
    const int* __restrict__ offsets, float* __restrict__ out)
{
    int node = blockIdx.x * 4 + (threadIdx.x >> 6);
    int lane = threadIdx.x & 63;
    if (node >= NNODES) return;
    int s0 = offsets[node], s1 = offsets[node + 1];
    float2 acc = make_float2(0.0f, 0.0f);
    int i = s0;
    for (; i + 8 <= s1; i += 8) {
        int2 p[8];
#pragma unroll
        for (int r = 0; r < 8; ++r) p[r] = pairs[i + r];
        float2 hv[8];
#pragma unroll
        for (int r = 0; r < 8; ++r)
            hv[r] = *(const float2*)(h + (size_t)p[r].y * 128 + lane * 2);
#pragma unroll
        for (int r = 0; r < 8; ++r) {
            float al = __int_as_float(p[r].x);
            acc.x = fmaf(al, hv[r].x, acc.x);
            acc.y = fmaf(al, hv[r].y, acc.y);
        }
    }
    for (; i < s1; ++i) {
        int2 p = pairs[i];
        float al = __int_as_float(p.x);
        float2 hj = *(const float2*)(h + (size_t)p.y * 128 + lane * 2);
        acc.x = fmaf(al, hj.x, acc.x);
        acc.y = fmaf(al, hj.y, acc.y);
    }
    *(float2*)(out + (size_t)node * 128 + lane * 2) = acc;
}

// ---------------------------------------------------------------------------
extern "C" void kernel_launch(void* const* d_in, const int* in_sizes, int n_in,
                              void* d_out, int out_size, void* d_ws, size_t ws_size,
                              hipStream_t stream)
{
    const float* h    = (const float*)d_in[0];
    const int*   eidx = (const int*)d_in[1];
    const float* ea   = (const float*)d_in[2];
    const float* W1   = (const float*)d_in[3];
    const float* b1   = (const float*)d_in[4];
    const float* W2   = (const float*)d_in[5];
    const float* b2   = (const float*)d_in[6];
    float* out = (float*)d_out;

    char* ws = (char*)d_ws;
    unsigned short* Hab = (unsigned short*)(ws);       // 25,600,000
    float* a_arr   = (float*)(ws + 25600000);          // 3,200,000
    int2*  pairs   = (int2*) (ws + 28800000);          // 6,400,000 (alpha,col)
    int*   offsets = (int*)  (ws + 35200000);          // 200,004 (padded)
    int*   cursor  = (int*)  (ws + 35400192);          // 200,000 (histogram too)
    float* bmax    = (float*)(ws + 35600384);          // 25,000 (pad 25,600)
    float* bsumE   = (float*)(ws + 35625984);          // 25,000 (pad 25,600)
    float* mz      = (float*)(ws + 35651584);          // 64
    unsigned short* Wt = (unsigned short*)(ws + 35651648); // 32,768
    int*   bsum_s  = (int*)  (ws + 35684416);          // 784 (pad 1024)
    int*   bpre_s  = (int*)  (ws + 35685440);          // 784 (pad 1024)

    hipMemsetAsync(cursor, 0, NNODES * sizeof(int), stream);

    k_prep<<<16, 256, 0, stream>>>(W1, Wt);
    k_gemm_node<<<dim3((NNODES + 127) / 128, 2), 256, 0, stream>>>(h, W1, b1, Hab);

    // big edge kernel: GEMM + attention logits + fused histogram + block partials
    k_edge_mfma<<<NB_EDGE, 256, 0, stream>>>(ea, eidx, Wt, W2, b2, Hab,
                                             a_arr, cursor, bmax, bsumE);

    k_scan_blk<<<NB_SCAN, 256, 0, stream>>>(cursor, offsets, bsum_s);
    k_scan_top<<<1, 256, 0, stream>>>(bsum_s, bpre_s, offsets);
    k_scan_add<<<NB_SCAN, 256, 0, stream>>>(offsets, bpre_s);
    hipMemsetAsync(cursor, 0, NNODES * sizeof(int), stream);

    k_final<<<1, 1024, 0, stream>>>(bmax, bsumE, mz);
    k_scatter<<<(NEDGES + 255) / 256, 256, 0, stream>>>(eidx, offsets, cursor,
                                                        a_arr, mz, pairs);
    k_agg<<<(NNODES + 3) / 4, 256, 0, stream>>>(h, pairs, offsets, out);
}